// Round 1
// baseline (519.975 us; speedup 1.0000x reference)
//
#include <hip/hip_runtime.h>
#include <math.h>

#define ALPHA 0.2f

__device__ __forceinline__ unsigned fkey(float x) {
  unsigned b = __float_as_uint(x);
  return (b & 0x80000000u) ? ~b : (b | 0x80000000u);
}
__device__ __forceinline__ float kinv(unsigned k) {
  unsigned b = (k & 0x80000000u) ? (k & 0x7FFFFFFFu) : ~k;
  return __uint_as_float(b);
}
__device__ __forceinline__ unsigned short f2bf(float x) {
  unsigned u = __float_as_uint(x);
  unsigned r = (u + 0x7FFFu + ((u >> 16) & 1u)) >> 16;
  return (unsigned short)r;
}
__device__ __forceinline__ float bf2f(unsigned s) { return __uint_as_float(s << 16); }

// ---------------- init ----------------
__global__ void init_k(unsigned* mkey, float* denom, unsigned* cnt, int N) {
  int i = blockIdx.x * blockDim.x + threadIdx.x;
  if (i < N) { mkey[i] = 0u; denom[i] = 0.0f; cnt[i] = 0u; }
}

// ---------------- GEMM h=seq@W fused with f1/f2 + bf16(h) ----------------
// BM=64, BK=32, BN=128 fixed. 256 threads: tc=tid&31 (4 cols each), tr=tid>>5 (8 rows each).
__global__ __launch_bounds__(256) void gemm_fused(
    const float* __restrict__ seq, const float* __restrict__ W,
    const float* __restrict__ a1w, const float* __restrict__ a1b,
    const float* __restrict__ a2w, const float* __restrict__ a2b,
    unsigned* __restrict__ hb, float* __restrict__ f1, float* __restrict__ f2, int N) {
  __shared__ float sA[64][33];
  __shared__ float sW[32][128];
  const int tid = threadIdx.x;
  const int tc = tid & 31, tr = tid >> 5;
  const int rowbase = blockIdx.x * 64;
  float acc[8][4] = {};

  for (int k0 = 0; k0 < 256; k0 += 32) {
    // stage A: 64x32 floats = 512 float4, 2 per thread
    #pragma unroll
    for (int l = 0; l < 2; ++l) {
      int fi = tid + l * 256;
      int r = fi >> 3, kg = fi & 7;
      int gr = rowbase + r; if (gr > N - 1) gr = N - 1;
      float4 v = *reinterpret_cast<const float4*>(seq + (size_t)gr * 256 + k0 + kg * 4);
      sA[r][kg * 4 + 0] = v.x; sA[r][kg * 4 + 1] = v.y;
      sA[r][kg * 4 + 2] = v.z; sA[r][kg * 4 + 3] = v.w;
    }
    // stage W: 32x128 floats = 1024 float4, 4 per thread
    #pragma unroll
    for (int l = 0; l < 4; ++l) {
      int fi = tid + l * 256;
      int kk = fi >> 5, cg = fi & 31;
      float4 v = *reinterpret_cast<const float4*>(W + (size_t)(k0 + kk) * 128 + cg * 4);
      *reinterpret_cast<float4*>(&sW[kk][cg * 4]) = v;
    }
    __syncthreads();
    #pragma unroll 4
    for (int kk = 0; kk < 32; ++kk) {
      float b0 = sW[kk][tc * 4 + 0], b1 = sW[kk][tc * 4 + 1];
      float b2 = sW[kk][tc * 4 + 2], b3 = sW[kk][tc * 4 + 3];
      #pragma unroll
      for (int j = 0; j < 8; ++j) {
        float a = sA[tr * 8 + j][kk];
        acc[j][0] += a * b0; acc[j][1] += a * b1;
        acc[j][2] += a * b2; acc[j][3] += a * b3;
      }
    }
    __syncthreads();
  }

  // epilogue: bf16 pack of h, plus f1/f2 via per-row reduction over the 32 col-threads
  float a1c[4], a2c[4];
  #pragma unroll
  for (int q = 0; q < 4; ++q) { a1c[q] = a1w[tc * 4 + q]; a2c[q] = a2w[tc * 4 + q]; }
  float b1s = a1b[0], b2s = a2b[0];

  #pragma unroll
  for (int j = 0; j < 8; ++j) {
    int gr = rowbase + tr * 8 + j;
    float p1 = acc[j][0] * a1c[0] + acc[j][1] * a1c[1] + acc[j][2] * a1c[2] + acc[j][3] * a1c[3];
    float p2 = acc[j][0] * a2c[0] + acc[j][1] * a2c[1] + acc[j][2] * a2c[2] + acc[j][3] * a2c[3];
    #pragma unroll
    for (int off = 16; off > 0; off >>= 1) {
      p1 += __shfl_xor(p1, off);
      p2 += __shfl_xor(p2, off);
    }
    if (gr < N) {
      unsigned p0 = (unsigned)f2bf(acc[j][0]) | ((unsigned)f2bf(acc[j][1]) << 16);
      unsigned q0 = (unsigned)f2bf(acc[j][2]) | ((unsigned)f2bf(acc[j][3]) << 16);
      uint2 pk; pk.x = p0; pk.y = q0;
      *reinterpret_cast<uint2*>(hb + (size_t)gr * 64 + tc * 2) = pk;
      if (tc == 0) { f1[gr] = p1 + b1s; f2[gr] = p2 + b2s; }
    }
  }
}

// ---------------- edge pass 1: logits, segment-max (keyed atomicMax), histogram ----------------
__global__ void edge_pass1(const int* __restrict__ row, const int* __restrict__ col,
                           const float* __restrict__ w, const float* __restrict__ f1,
                           const float* __restrict__ f2, float* __restrict__ vv,
                           unsigned* __restrict__ mkey, unsigned* __restrict__ cnt, int E) {
  int t = blockIdx.x * blockDim.x + threadIdx.x;
  if (t >= E) return;
  int r = row[t], c = col[t];
  float x = f1[r] + f2[c];
  x = x > 0.0f ? x : ALPHA * x;
  x *= w[t];
  vv[t] = x;
  atomicMax(&mkey[r], fkey(x));
  atomicAdd(&cnt[r], 1u);
}

// ---------------- scan (3-kernel block scan over N+1 entries) ----------------
__global__ __launch_bounds__(256) void scan_reduce(const unsigned* __restrict__ cnt,
                                                   unsigned* __restrict__ bsum, int N) {
  int i = blockIdx.x * 256 + threadIdx.x;
  unsigned v = (i < N) ? cnt[i] : 0u;
  #pragma unroll
  for (int o = 32; o > 0; o >>= 1) v += __shfl_down(v, o);
  __shared__ unsigned ws4[4];
  int lane = threadIdx.x & 63, wid = threadIdx.x >> 6;
  if (lane == 0) ws4[wid] = v;
  __syncthreads();
  if (threadIdx.x == 0) bsum[blockIdx.x] = ws4[0] + ws4[1] + ws4[2] + ws4[3];
}

__global__ __launch_bounds__(256) void scan_top(unsigned* bsum, int nb) {
  __shared__ unsigned ls[256];
  int t = threadIdx.x;
  unsigned x = (t < nb) ? bsum[t] : 0u;
  ls[t] = x;
  __syncthreads();
  for (int off = 1; off < 256; off <<= 1) {
    unsigned y = (t >= off) ? ls[t - off] : 0u;
    __syncthreads();
    ls[t] += y;
    __syncthreads();
  }
  if (t < nb) bsum[t] = ls[t] - x;  // exclusive
}

__global__ __launch_bounds__(256) void scan_apply(const unsigned* __restrict__ cnt,
                                                  const unsigned* __restrict__ boff,
                                                  unsigned* __restrict__ rowstart,
                                                  unsigned* __restrict__ wcount, int N) {
  __shared__ unsigned ls[256];
  int t = threadIdx.x;
  int i = blockIdx.x * 256 + t;
  unsigned x = (i < N) ? cnt[i] : 0u;
  ls[t] = x;
  __syncthreads();
  for (int off = 1; off < 256; off <<= 1) {
    unsigned y = (t >= off) ? ls[t - off] : 0u;
    __syncthreads();
    ls[t] += y;
    __syncthreads();
  }
  unsigned excl = ls[t] - x + boff[blockIdx.x];
  if (i <= N) rowstart[i] = excl;
  if (i < N) wcount[i] = excl;
}

// ---------------- edge pass 2: exp, segment-sum denom, CSR scatter ----------------
__global__ void edge_pass2(const int* __restrict__ row, const int* __restrict__ col,
                           const float* __restrict__ vv, const unsigned* __restrict__ mkey,
                           float* __restrict__ denom, unsigned* __restrict__ wcount,
                           float* __restrict__ ev, int* __restrict__ ecols, int E) {
  int t = blockIdx.x * blockDim.x + threadIdx.x;
  if (t >= E) return;
  int r = row[t];
  float m = kinv(mkey[r]);
  float e = __expf(vv[t] - m);
  atomicAdd(&denom[r], e);
  unsigned pos = atomicAdd(&wcount[r], 1u);
  ev[pos] = e;
  ecols[pos] = col[t];
}

// ---------------- pull SpMM: one wave per row ----------------
__global__ __launch_bounds__(256) void spmm(const unsigned* __restrict__ rowstart,
                                            const float* __restrict__ denom,
                                            const float* __restrict__ ev,
                                            const int* __restrict__ ecols,
                                            const unsigned* __restrict__ hb,
                                            const float* __restrict__ bias,
                                            float* __restrict__ out, int N) {
  int wid = (blockIdx.x * 256 + threadIdx.x) >> 6;
  int lane = threadIdx.x & 63;
  if (wid >= N) return;
  int s = rowstart[wid], e = rowstart[wid + 1];
  float rd = 1.0f / fmaxf(denom[wid], 1e-38f);
  float acc0 = 0.0f, acc1 = 0.0f;
  for (int j = s; j < e; ++j) {
    float cf = ev[j];
    unsigned hv = hb[(size_t)ecols[j] * 64 + lane];
    acc0 += cf * bf2f(hv & 0xFFFFu);
    acc1 += cf * bf2f(hv >> 16);
  }
  acc0 *= rd; acc1 *= rd;
  float o0 = fmaxf(acc0 + bias[2 * lane], 0.0f);
  float o1 = fmaxf(acc1 + bias[2 * lane + 1], 0.0f);
  float2 o; o.x = o0; o.y = o1;
  *reinterpret_cast<float2*>(out + (size_t)wid * 128 + 2 * lane) = o;
}

extern "C" void kernel_launch(void* const* d_in, const int* in_sizes, int n_in,
                              void* d_out, int out_size, void* d_ws, size_t ws_size,
                              hipStream_t stream) {
  const float* seq    = (const float*)d_in[0];
  const int*   erow   = (const int*)d_in[1];
  const int*   ecol   = (const int*)d_in[2];
  const float* weight = (const float*)d_in[3];
  const float* W      = (const float*)d_in[4];
  const float* a1w    = (const float*)d_in[5];
  const float* a1b    = (const float*)d_in[6];
  const float* a2w    = (const float*)d_in[7];
  const float* a2b    = (const float*)d_in[8];
  const float* bias   = (const float*)d_in[9];
  const int N = in_sizes[0] / 256;
  const int E = in_sizes[1];
  float* out = (float*)d_out;

  char* p = (char*)d_ws;
  auto alloc = [&](size_t bytes) -> char* {
    char* q = p;
    p += (bytes + 255) & ~(size_t)255;
    return q;
  };
  unsigned* hb       = (unsigned*)alloc((size_t)N * 64 * 4);
  float*    f1       = (float*)alloc((size_t)N * 4);
  float*    f2       = (float*)alloc((size_t)N * 4);
  unsigned* mkey     = (unsigned*)alloc((size_t)N * 4);
  float*    denom    = (float*)alloc((size_t)N * 4);
  unsigned* cnt      = (unsigned*)alloc((size_t)N * 4);
  unsigned* rowstart = (unsigned*)alloc((size_t)(N + 1) * 4);
  unsigned* wcount   = (unsigned*)alloc((size_t)N * 4);
  unsigned* bsum     = (unsigned*)alloc((size_t)1024);
  float*    vv       = (float*)alloc((size_t)E * 4);
  float*    ev       = (float*)alloc((size_t)E * 4);
  int*      ecs      = (int*)alloc((size_t)E * 4);

  const int NB = (N + 1 + 255) / 256;  // scan blocks (covers rowstart[N])

  init_k<<<(N + 255) / 256, 256, 0, stream>>>(mkey, denom, cnt, N);
  gemm_fused<<<(N + 63) / 64, 256, 0, stream>>>(seq, W, a1w, a1b, a2w, a2b, hb, f1, f2, N);
  edge_pass1<<<(E + 255) / 256, 256, 0, stream>>>(erow, ecol, weight, f1, f2, vv, mkey, cnt, E);
  scan_reduce<<<NB, 256, 0, stream>>>(cnt, bsum, N);
  scan_top<<<1, 256, 0, stream>>>(bsum, NB);
  scan_apply<<<NB, 256, 0, stream>>>(cnt, bsum, rowstart, wcount, N);
  edge_pass2<<<(E + 255) / 256, 256, 0, stream>>>(erow, ecol, vv, mkey, denom, wcount, ev, ecs, E);
  spmm<<<(N * 64 + 255) / 256, 256, 0, stream>>>(rowstart, denom, ev, ecs, hb, bias, out, N);
}

// Round 4
// 374.701 us; speedup vs baseline: 1.3877x; 1.3877x over previous
//
#include <hip/hip_runtime.h>
#include <math.h>

#define ALPHA 0.2f

__device__ __forceinline__ unsigned short f2bf(float x) {
  unsigned u = __float_as_uint(x);
  unsigned r = (u + 0x7FFFu + ((u >> 16) & 1u)) >> 16;
  return (unsigned short)r;
}
__device__ __forceinline__ float bf2f(unsigned s) { return __uint_as_float(s << 16); }

// ---------------- init ----------------
__global__ void init_k(unsigned* cnt, int N) {
  int i = blockIdx.x * blockDim.x + threadIdx.x;
  if (i < N) cnt[i] = 0u;
}

// ---------------- GEMM h=seq@W fused with f1/f2 + bf16(h) ----------------
__global__ __launch_bounds__(256) void gemm_fused(
    const float* __restrict__ seq, const float* __restrict__ W,
    const float* __restrict__ a1w, const float* __restrict__ a1b,
    const float* __restrict__ a2w, const float* __restrict__ a2b,
    unsigned* __restrict__ hb, float* __restrict__ f1, float* __restrict__ f2, int N) {
  __shared__ float sA[64][33];
  __shared__ float sW[32][128];
  const int tid = threadIdx.x;
  const int tc = tid & 31, tr = tid >> 5;
  const int rowbase = blockIdx.x * 64;
  float acc[8][4] = {};

  for (int k0 = 0; k0 < 256; k0 += 32) {
    #pragma unroll
    for (int l = 0; l < 2; ++l) {
      int fi = tid + l * 256;
      int r = fi >> 3, kg = fi & 7;
      int gr = rowbase + r; if (gr > N - 1) gr = N - 1;
      float4 v = *reinterpret_cast<const float4*>(seq + (size_t)gr * 256 + k0 + kg * 4);
      sA[r][kg * 4 + 0] = v.x; sA[r][kg * 4 + 1] = v.y;
      sA[r][kg * 4 + 2] = v.z; sA[r][kg * 4 + 3] = v.w;
    }
    #pragma unroll
    for (int l = 0; l < 4; ++l) {
      int fi = tid + l * 256;
      int kk = fi >> 5, cg = fi & 31;
      float4 v = *reinterpret_cast<const float4*>(W + (size_t)(k0 + kk) * 128 + cg * 4);
      *reinterpret_cast<float4*>(&sW[kk][cg * 4]) = v;
    }
    __syncthreads();
    #pragma unroll 4
    for (int kk = 0; kk < 32; ++kk) {
      float b0 = sW[kk][tc * 4 + 0], b1 = sW[kk][tc * 4 + 1];
      float b2 = sW[kk][tc * 4 + 2], b3 = sW[kk][tc * 4 + 3];
      #pragma unroll
      for (int j = 0; j < 8; ++j) {
        float a = sA[tr * 8 + j][kk];
        acc[j][0] += a * b0; acc[j][1] += a * b1;
        acc[j][2] += a * b2; acc[j][3] += a * b3;
      }
    }
    __syncthreads();
  }

  float a1c[4], a2c[4];
  #pragma unroll
  for (int q = 0; q < 4; ++q) { a1c[q] = a1w[tc * 4 + q]; a2c[q] = a2w[tc * 4 + q]; }
  float b1s = a1b[0], b2s = a2b[0];

  #pragma unroll
  for (int j = 0; j < 8; ++j) {
    int gr = rowbase + tr * 8 + j;
    float p1 = acc[j][0] * a1c[0] + acc[j][1] * a1c[1] + acc[j][2] * a1c[2] + acc[j][3] * a1c[3];
    float p2 = acc[j][0] * a2c[0] + acc[j][1] * a2c[1] + acc[j][2] * a2c[2] + acc[j][3] * a2c[3];
    #pragma unroll
    for (int off = 16; off > 0; off >>= 1) {
      p1 += __shfl_xor(p1, off);
      p2 += __shfl_xor(p2, off);
    }
    if (gr < N) {
      unsigned p0 = (unsigned)f2bf(acc[j][0]) | ((unsigned)f2bf(acc[j][1]) << 16);
      unsigned q0 = (unsigned)f2bf(acc[j][2]) | ((unsigned)f2bf(acc[j][3]) << 16);
      uint2 pk; pk.x = p0; pk.y = q0;
      *reinterpret_cast<uint2*>(hb + (size_t)gr * 64 + tc * 2) = pk;
      if (tc == 0) { f1[gr] = p1 + b1s; f2[gr] = p2 + b2s; }
    }
  }
}

// ---------------- histogram: 4 edges/thread ----------------
__global__ void hist_k(const int* __restrict__ row, unsigned* __restrict__ cnt, int E) {
  int t = blockIdx.x * blockDim.x + threadIdx.x;
  int base = t * 4;
  if (base + 3 < E) {
    int4 r = *reinterpret_cast<const int4*>(row + base);
    atomicAdd(&cnt[r.x], 1u);
    atomicAdd(&cnt[r.y], 1u);
    atomicAdd(&cnt[r.z], 1u);
    atomicAdd(&cnt[r.w], 1u);
  } else {
    for (int i = base; i < E; ++i) atomicAdd(&cnt[row[i]], 1u);
  }
}

// ---------------- scan (3-kernel block scan over N+1 entries) ----------------
__global__ __launch_bounds__(256) void scan_reduce(const unsigned* __restrict__ cnt,
                                                   unsigned* __restrict__ bsum, int N) {
  int i = blockIdx.x * 256 + threadIdx.x;
  unsigned v = (i < N) ? cnt[i] : 0u;
  #pragma unroll
  for (int o = 32; o > 0; o >>= 1) v += __shfl_down(v, o);
  __shared__ unsigned ws4[4];
  int lane = threadIdx.x & 63, wid = threadIdx.x >> 6;
  if (lane == 0) ws4[wid] = v;
  __syncthreads();
  if (threadIdx.x == 0) bsum[blockIdx.x] = ws4[0] + ws4[1] + ws4[2] + ws4[3];
}

__global__ __launch_bounds__(256) void scan_top(unsigned* bsum, int nb) {
  __shared__ unsigned ls[256];
  int t = threadIdx.x;
  unsigned x = (t < nb) ? bsum[t] : 0u;
  ls[t] = x;
  __syncthreads();
  for (int off = 1; off < 256; off <<= 1) {
    unsigned y = (t >= off) ? ls[t - off] : 0u;
    __syncthreads();
    ls[t] += y;
    __syncthreads();
  }
  if (t < nb) bsum[t] = ls[t] - x;  // exclusive
}

__global__ __launch_bounds__(256) void scan_apply(const unsigned* __restrict__ cnt,
                                                  const unsigned* __restrict__ boff,
                                                  unsigned* __restrict__ rowstart,
                                                  unsigned* __restrict__ wcount, int N) {
  __shared__ unsigned ls[256];
  int t = threadIdx.x;
  int i = blockIdx.x * 256 + t;
  unsigned x = (i < N) ? cnt[i] : 0u;
  ls[t] = x;
  __syncthreads();
  for (int off = 1; off < 256; off <<= 1) {
    unsigned y = (t >= off) ? ls[t - off] : 0u;
    __syncthreads();
    ls[t] += y;
    __syncthreads();
  }
  unsigned excl = ls[t] - x + boff[blockIdx.x];
  if (i <= N) rowstart[i] = excl;
  if (i < N) wcount[i] = excl;
}

// ---------------- scatter: logit + CSR scatter (one uint2 store/edge) ----------------
__global__ void scatter_k(const int* __restrict__ row, const int* __restrict__ col,
                          const float* __restrict__ w, const float* __restrict__ f1,
                          const float* __restrict__ f2, unsigned* __restrict__ wcount,
                          uint2* __restrict__ eb, int E) {
  int t = blockIdx.x * blockDim.x + threadIdx.x;
  int base = t * 4;
  if (base >= E) return;
  if (base + 3 < E) {
    int4 r4 = *reinterpret_cast<const int4*>(row + base);
    int4 c4 = *reinterpret_cast<const int4*>(col + base);
    float4 w4 = *reinterpret_cast<const float4*>(w + base);
    int rr[4] = {r4.x, r4.y, r4.z, r4.w};
    int cc[4] = {c4.x, c4.y, c4.z, c4.w};
    float ww[4] = {w4.x, w4.y, w4.z, w4.w};
    #pragma unroll
    for (int i = 0; i < 4; ++i) {
      float x = f1[rr[i]] + f2[cc[i]];
      x = x > 0.0f ? x : ALPHA * x;
      x *= ww[i];
      unsigned pos = atomicAdd(&wcount[rr[i]], 1u);
      uint2 pk; pk.x = __float_as_uint(x); pk.y = (unsigned)cc[i];
      eb[pos] = pk;
    }
  } else {
    for (int i = base; i < E; ++i) {
      int r = row[i], c = col[i];
      float x = f1[r] + f2[c];
      x = x > 0.0f ? x : ALPHA * x;
      x *= w[i];
      unsigned pos = atomicAdd(&wcount[r], 1u);
      uint2 pk; pk.x = __float_as_uint(x); pk.y = (unsigned)c;
      eb[pos] = pk;
    }
  }
}

// ---------------- fused softmax + pull SpMM: one wave per row ----------------
__global__ __launch_bounds__(256) void spmm(const unsigned* __restrict__ rowstart,
                                            const uint2* __restrict__ eb,
                                            const unsigned* __restrict__ hb,
                                            const float* __restrict__ bias,
                                            float* __restrict__ out, int N) {
  int wid = (blockIdx.x * 256 + threadIdx.x) >> 6;
  int lane = threadIdx.x & 63;
  if (wid >= N) return;
  int s = (int)rowstart[wid], e = (int)rowstart[wid + 1];

  // phase 1: row max + denom via lane-strided passes (coalesced 8B loads)
  float m = -3.4e38f;
  for (int j = s + lane; j < e; j += 64) m = fmaxf(m, __uint_as_float(eb[j].x));
  #pragma unroll
  for (int off = 32; off > 0; off >>= 1) m = fmaxf(m, __shfl_xor(m, off));
  float dsum = 0.0f;
  for (int j = s + lane; j < e; j += 64) dsum += __expf(__uint_as_float(eb[j].x) - m);
  #pragma unroll
  for (int off = 32; off > 0; off >>= 1) dsum += __shfl_xor(dsum, off);
  float rd = 1.0f / fmaxf(dsum, 1e-38f);

  // phase 2: accumulate coef * h[col]
  float acc0 = 0.0f, acc1 = 0.0f;
  for (int j = s; j < e; ++j) {
    uint2 ej = eb[j];  // wave-uniform address -> broadcast
    float cf = __expf(__uint_as_float(ej.x) - m);
    unsigned hv = hb[(size_t)ej.y * 64 + lane];
    acc0 += cf * bf2f(hv & 0xFFFFu);
    acc1 += cf * bf2f(hv >> 16);
  }
  acc0 *= rd; acc1 *= rd;
  float o0 = fmaxf(acc0 + bias[2 * lane], 0.0f);
  float o1 = fmaxf(acc1 + bias[2 * lane + 1], 0.0f);
  float2 o; o.x = o0; o.y = o1;
  *reinterpret_cast<float2*>(out + (size_t)wid * 128 + 2 * lane) = o;
}

extern "C" void kernel_launch(void* const* d_in, const int* in_sizes, int n_in,
                              void* d_out, int out_size, void* d_ws, size_t ws_size,
                              hipStream_t stream) {
  const float* seq    = (const float*)d_in[0];
  const int*   erow   = (const int*)d_in[1];
  const int*   ecol   = (const int*)d_in[2];
  const float* weight = (const float*)d_in[3];
  const float* W      = (const float*)d_in[4];
  const float* a1w    = (const float*)d_in[5];
  const float* a1b    = (const float*)d_in[6];
  const float* a2w    = (const float*)d_in[7];
  const float* a2b    = (const float*)d_in[8];
  const float* bias   = (const float*)d_in[9];
  const int N = in_sizes[0] / 256;
  const int E = in_sizes[1];
  float* out = (float*)d_out;

  char* p = (char*)d_ws;
  auto alloc = [&](size_t bytes) -> char* {
    char* q = p;
    p += (bytes + 255) & ~(size_t)255;
    return q;
  };
  unsigned* hb       = (unsigned*)alloc((size_t)N * 64 * 4);
  float*    f1       = (float*)alloc((size_t)N * 4);
  float*    f2       = (float*)alloc((size_t)N * 4);
  unsigned* cnt      = (unsigned*)alloc((size_t)N * 4);
  unsigned* rowstart = (unsigned*)alloc((size_t)(N + 1) * 4);
  unsigned* wcount   = (unsigned*)alloc((size_t)N * 4);
  unsigned* bsum     = (unsigned*)alloc((size_t)1024);
  uint2*    eb       = (uint2*)alloc((size_t)E * 8);

  const int NB = (N + 1 + 255) / 256;

  init_k<<<(N + 255) / 256, 256, 0, stream>>>(cnt, N);
  gemm_fused<<<(N + 63) / 64, 256, 0, stream>>>(seq, W, a1w, a1b, a2w, a2b, hb, f1, f2, N);
  hist_k<<<(E / 4 + 255) / 256, 256, 0, stream>>>(erow, cnt, E);
  scan_reduce<<<NB, 256, 0, stream>>>(cnt, bsum, N);
  scan_top<<<1, 256, 0, stream>>>(bsum, NB);
  scan_apply<<<NB, 256, 0, stream>>>(cnt, bsum, rowstart, wcount, N);
  scatter_k<<<(E / 4 + 255) / 256, 256, 0, stream>>>(erow, ecol, weight, f1, f2, wcount, eb, E);
  spmm<<<(N * 64 + 255) / 256, 256, 0, stream>>>(rowstart, eb, hb, bias, out, N);
}

// Round 8
// 277.828 us; speedup vs baseline: 1.8716x; 1.3487x over previous
//
#include <hip/hip_runtime.h>
#include <math.h>

#define ALPHA 0.2f

__device__ __forceinline__ unsigned short f2bf(float x) {
  unsigned u = __float_as_uint(x);
  unsigned r = (u + 0x7FFFu + ((u >> 16) & 1u)) >> 16;
  return (unsigned short)r;
}
__device__ __forceinline__ float bf2f(unsigned s) { return __uint_as_float(s << 16); }

// ---------------- init ----------------
__global__ void init_k(unsigned* cnt, int N) {
  int i = blockIdx.x * blockDim.x + threadIdx.x;
  if (i < N) cnt[i] = 0u;
}

// ---------------- GEMM h=seq@W fused with f1/f2 + bf16(h) ----------------
__global__ __launch_bounds__(256) void gemm_fused(
    const float* __restrict__ seq, const float* __restrict__ W,
    const float* __restrict__ a1w, const float* __restrict__ a1b,
    const float* __restrict__ a2w, const float* __restrict__ a2b,
    unsigned* __restrict__ hb, float* __restrict__ f1, float* __restrict__ f2, int N) {
  __shared__ float sA[64][33];
  __shared__ float sW[32][128];
  const int tid = threadIdx.x;
  const int tc = tid & 31, tr = tid >> 5;
  const int rowbase = blockIdx.x * 64;
  float acc[8][4] = {};

  for (int k0 = 0; k0 < 256; k0 += 32) {
    #pragma unroll
    for (int l = 0; l < 2; ++l) {
      int fi = tid + l * 256;
      int r = fi >> 3, kg = fi & 7;
      int gr = rowbase + r; if (gr > N - 1) gr = N - 1;
      float4 v = *reinterpret_cast<const float4*>(seq + (size_t)gr * 256 + k0 + kg * 4);
      sA[r][kg * 4 + 0] = v.x; sA[r][kg * 4 + 1] = v.y;
      sA[r][kg * 4 + 2] = v.z; sA[r][kg * 4 + 3] = v.w;
    }
    #pragma unroll
    for (int l = 0; l < 4; ++l) {
      int fi = tid + l * 256;
      int kk = fi >> 5, cg = fi & 31;
      float4 v = *reinterpret_cast<const float4*>(W + (size_t)(k0 + kk) * 128 + cg * 4);
      *reinterpret_cast<float4*>(&sW[kk][cg * 4]) = v;
    }
    __syncthreads();
    #pragma unroll 4
    for (int kk = 0; kk < 32; ++kk) {
      float b0 = sW[kk][tc * 4 + 0], b1 = sW[kk][tc * 4 + 1];
      float b2 = sW[kk][tc * 4 + 2], b3 = sW[kk][tc * 4 + 3];
      #pragma unroll
      for (int j = 0; j < 8; ++j) {
        float a = sA[tr * 8 + j][kk];
        acc[j][0] += a * b0; acc[j][1] += a * b1;
        acc[j][2] += a * b2; acc[j][3] += a * b3;
      }
    }
    __syncthreads();
  }

  float a1c[4], a2c[4];
  #pragma unroll
  for (int q = 0; q < 4; ++q) { a1c[q] = a1w[tc * 4 + q]; a2c[q] = a2w[tc * 4 + q]; }
  float b1s = a1b[0], b2s = a2b[0];

  #pragma unroll
  for (int j = 0; j < 8; ++j) {
    int gr = rowbase + tr * 8 + j;
    float p1 = acc[j][0] * a1c[0] + acc[j][1] * a1c[1] + acc[j][2] * a1c[2] + acc[j][3] * a1c[3];
    float p2 = acc[j][0] * a2c[0] + acc[j][1] * a2c[1] + acc[j][2] * a2c[2] + acc[j][3] * a2c[3];
    #pragma unroll
    for (int off = 16; off > 0; off >>= 1) {
      p1 += __shfl_xor(p1, off);
      p2 += __shfl_xor(p2, off);
    }
    if (gr < N) {
      unsigned p0 = (unsigned)f2bf(acc[j][0]) | ((unsigned)f2bf(acc[j][1]) << 16);
      unsigned q0 = (unsigned)f2bf(acc[j][2]) | ((unsigned)f2bf(acc[j][3]) << 16);
      uint2 pk; pk.x = p0; pk.y = q0;
      *reinterpret_cast<uint2*>(hb + (size_t)gr * 64 + tc * 2) = pk;
      if (tc == 0) { f1[gr] = p1 + b1s; f2[gr] = p2 + b2s; }
    }
  }
}

// ---------------- histogram: 4 edges/thread ----------------
__global__ void hist_k(const int* __restrict__ row, unsigned* __restrict__ cnt, int E) {
  int t = blockIdx.x * blockDim.x + threadIdx.x;
  int base = t * 4;
  if (base + 3 < E) {
    int4 r = *reinterpret_cast<const int4*>(row + base);
    atomicAdd(&cnt[r.x], 1u);
    atomicAdd(&cnt[r.y], 1u);
    atomicAdd(&cnt[r.z], 1u);
    atomicAdd(&cnt[r.w], 1u);
  } else {
    for (int i = base; i < E; ++i) atomicAdd(&cnt[row[i]], 1u);
  }
}

// ---------------- scan (3-kernel block scan over N+1 entries) ----------------
__global__ __launch_bounds__(256) void scan_reduce(const unsigned* __restrict__ cnt,
                                                   unsigned* __restrict__ bsum, int N) {
  int i = blockIdx.x * 256 + threadIdx.x;
  unsigned v = (i < N) ? cnt[i] : 0u;
  #pragma unroll
  for (int o = 32; o > 0; o >>= 1) v += __shfl_down(v, o);
  __shared__ unsigned ws4[4];
  int lane = threadIdx.x & 63, wid = threadIdx.x >> 6;
  if (lane == 0) ws4[wid] = v;
  __syncthreads();
  if (threadIdx.x == 0) bsum[blockIdx.x] = ws4[0] + ws4[1] + ws4[2] + ws4[3];
}

__global__ __launch_bounds__(256) void scan_top(unsigned* bsum, int nb) {
  __shared__ unsigned ls[256];
  int t = threadIdx.x;
  unsigned x = (t < nb) ? bsum[t] : 0u;
  ls[t] = x;
  __syncthreads();
  for (int off = 1; off < 256; off <<= 1) {
    unsigned y = (t >= off) ? ls[t - off] : 0u;
    __syncthreads();
    ls[t] += y;
    __syncthreads();
  }
  if (t < nb) bsum[t] = ls[t] - x;  // exclusive
}

__global__ __launch_bounds__(256) void scan_apply(const unsigned* __restrict__ cnt,
                                                  const unsigned* __restrict__ boff,
                                                  unsigned* __restrict__ rowstart,
                                                  unsigned* __restrict__ wcount, int N) {
  __shared__ unsigned ls[256];
  int t = threadIdx.x;
  int i = blockIdx.x * 256 + t;
  unsigned x = (i < N) ? cnt[i] : 0u;
  ls[t] = x;
  __syncthreads();
  for (int off = 1; off < 256; off <<= 1) {
    unsigned y = (t >= off) ? ls[t - off] : 0u;
    __syncthreads();
    ls[t] += y;
    __syncthreads();
  }
  unsigned excl = ls[t] - x + boff[blockIdx.x];
  if (i <= N) rowstart[i] = excl;
  if (i < N) wcount[i] = excl;
}

// ---------------- scatter: logit + CSR scatter (one uint2 store/edge) ----------------
__global__ void scatter_k(const int* __restrict__ row, const int* __restrict__ col,
                          const float* __restrict__ w, const float* __restrict__ f1,
                          const float* __restrict__ f2, unsigned* __restrict__ wcount,
                          uint2* __restrict__ eb, int E) {
  int t = blockIdx.x * blockDim.x + threadIdx.x;
  int base = t * 4;
  if (base >= E) return;
  if (base + 3 < E) {
    int4 r4 = *reinterpret_cast<const int4*>(row + base);
    int4 c4 = *reinterpret_cast<const int4*>(col + base);
    float4 w4 = *reinterpret_cast<const float4*>(w + base);
    int rr[4] = {r4.x, r4.y, r4.z, r4.w};
    int cc[4] = {c4.x, c4.y, c4.z, c4.w};
    float ww[4] = {w4.x, w4.y, w4.z, w4.w};
    #pragma unroll
    for (int i = 0; i < 4; ++i) {
      float x = f1[rr[i]] + f2[cc[i]];
      x = x > 0.0f ? x : ALPHA * x;
      x *= ww[i];
      unsigned pos = atomicAdd(&wcount[rr[i]], 1u);
      uint2 pk; pk.x = __float_as_uint(x); pk.y = (unsigned)cc[i];
      eb[pos] = pk;
    }
  } else {
    for (int i = base; i < E; ++i) {
      int r = row[i], c = col[i];
      float x = f1[r] + f2[c];
      x = x > 0.0f ? x : ALPHA * x;
      x *= w[i];
      unsigned pos = atomicAdd(&wcount[r], 1u);
      uint2 pk; pk.x = __float_as_uint(x); pk.y = (unsigned)c;
      eb[pos] = pk;
    }
  }
}

// ---------------- fused softmax + pull SpMM ----------------
// One wave per row; 4 quarter-waves (16 lanes x uint4 = 256B) gather 4 edges'
// h-rows simultaneously. eb read ONCE per lane; softmax via shuffles.
// NOTE: inner edge loop must be WAVE-UNIFORM (bk over uniform nloc) so that
// __shfl sources are always active lanes; k<nloc predicates only the gather.
__global__ __launch_bounds__(256) void spmm(const unsigned* __restrict__ rowstart,
                                            const uint2* __restrict__ eb,
                                            const unsigned* __restrict__ hb,
                                            const float* __restrict__ bias,
                                            float* __restrict__ out, int N) {
  int wid = (blockIdx.x * 256 + threadIdx.x) >> 6;
  int lane = threadIdx.x & 63;
  if (wid >= N) return;
  const int s = (int)rowstart[wid], e = (int)rowstart[wid + 1];
  const int qw = lane >> 4;   // quarter id 0..3
  const int ql = lane & 15;   // lane within quarter

  // ---- load chunk 0 into registers (common case: whole row) ----
  int j0 = s + lane;
  float x0 = -3.4e38f;
  int c0 = 0;
  if (j0 < e) {
    uint2 t = eb[j0];
    x0 = __uint_as_float(t.x);
    c0 = (int)t.y;
  }

  // ---- online max/denom across chunks ----
  float cm = x0;
  #pragma unroll
  for (int off = 32; off > 0; off >>= 1) cm = fmaxf(cm, __shfl_xor(cm, off));
  float m = cm;
  float ex = (j0 < e) ? __expf(x0 - m) : 0.0f;
  float cs = ex;
  #pragma unroll
  for (int off = 32; off > 0; off >>= 1) cs += __shfl_xor(cs, off);
  float dsum = cs;
  for (int base = s + 64; base < e; base += 64) {  // rare (>64-edge rows)
    int j = base + lane;
    float x = (j < e) ? __uint_as_float(eb[j].x) : -3.4e38f;
    float c2 = x;
    #pragma unroll
    for (int off = 32; off > 0; off >>= 1) c2 = fmaxf(c2, __shfl_xor(c2, off));
    float mn = fmaxf(m, c2);
    float e2 = (j < e) ? __expf(x - mn) : 0.0f;
    #pragma unroll
    for (int off = 32; off > 0; off >>= 1) e2 += __shfl_xor(e2, off);
    dsum = dsum * __expf(m - mn) + e2;
    m = mn;
  }
  float rd = 1.0f / fmaxf(dsum, 1e-38f);

  // ---- accumulate: quarter qw handles edges k = bk + qw, bk wave-uniform ----
  float acc[8] = {};
  float cf_reg = (j0 < e) ? __expf(x0 - m) * rd : 0.0f;
  int c_reg = c0;
  for (int base = s; base < e; base += 64) {
    if (base != s) {  // reload for rare multi-chunk rows
      int j = base + lane;
      if (j < e) {
        uint2 t = eb[j];
        cf_reg = __expf(__uint_as_float(t.x) - m) * rd;
        c_reg = (int)t.y;
      } else {
        cf_reg = 0.0f; c_reg = 0;
      }
    }
    int nloc = e - base; if (nloc > 64) nloc = 64;
    for (int bk = 0; bk < nloc; bk += 4) {  // wave-uniform trip count
      int k = bk + qw;                       // may exceed nloc by up to 3
      int ksrc = (k < 64) ? k : 0;           // clamp shfl source
      float cfk = __shfl(cf_reg, ksrc);      // full exec mask here
      int ck = __shfl(c_reg, ksrc);
      if (k < nloc) {
        const uint4 hv = *reinterpret_cast<const uint4*>(hb + (size_t)ck * 64 + ql * 4);
        acc[0] += cfk * bf2f(hv.x & 0xFFFFu); acc[1] += cfk * bf2f(hv.x >> 16);
        acc[2] += cfk * bf2f(hv.y & 0xFFFFu); acc[3] += cfk * bf2f(hv.y >> 16);
        acc[4] += cfk * bf2f(hv.z & 0xFFFFu); acc[5] += cfk * bf2f(hv.z >> 16);
        acc[6] += cfk * bf2f(hv.w & 0xFFFFu); acc[7] += cfk * bf2f(hv.w >> 16);
      }
    }
  }

  // ---- cross-quarter reduction: lanes {ql, ql+16, ql+32, ql+48} hold same d-slice ----
  #pragma unroll
  for (int i = 0; i < 8; ++i) {
    acc[i] += __shfl_xor(acc[i], 16);
    acc[i] += __shfl_xor(acc[i], 32);
  }

  if (qw == 0) {
    const int d0 = ql * 8;
    float4 b0 = *reinterpret_cast<const float4*>(bias + d0);
    float4 b1 = *reinterpret_cast<const float4*>(bias + d0 + 4);
    float4 o0, o1;
    o0.x = fmaxf(acc[0] + b0.x, 0.0f); o0.y = fmaxf(acc[1] + b0.y, 0.0f);
    o0.z = fmaxf(acc[2] + b0.z, 0.0f); o0.w = fmaxf(acc[3] + b0.w, 0.0f);
    o1.x = fmaxf(acc[4] + b1.x, 0.0f); o1.y = fmaxf(acc[5] + b1.y, 0.0f);
    o1.z = fmaxf(acc[6] + b1.z, 0.0f); o1.w = fmaxf(acc[7] + b1.w, 0.0f);
    *reinterpret_cast<float4*>(out + (size_t)wid * 128 + d0) = o0;
    *reinterpret_cast<float4*>(out + (size_t)wid * 128 + d0 + 4) = o1;
  }
}

extern "C" void kernel_launch(void* const* d_in, const int* in_sizes, int n_in,
                              void* d_out, int out_size, void* d_ws, size_t ws_size,
                              hipStream_t stream) {
  const float* seq    = (const float*)d_in[0];
  const int*   erow   = (const int*)d_in[1];
  const int*   ecol   = (const int*)d_in[2];
  const float* weight = (const float*)d_in[3];
  const float* W      = (const float*)d_in[4];
  const float* a1w    = (const float*)d_in[5];
  const float* a1b    = (const float*)d_in[6];
  const float* a2w    = (const float*)d_in[7];
  const float* a2b    = (const float*)d_in[8];
  const float* bias   = (const float*)d_in[9];
  const int N = in_sizes[0] / 256;
  const int E = in_sizes[1];
  float* out = (float*)d_out;

  char* p = (char*)d_ws;
  auto alloc = [&](size_t bytes) -> char* {
    char* q = p;
    p += (bytes + 255) & ~(size_t)255;
    return q;
  };
  unsigned* hb       = (unsigned*)alloc((size_t)N * 64 * 4);
  float*    f1       = (float*)alloc((size_t)N * 4);
  float*    f2       = (float*)alloc((size_t)N * 4);
  unsigned* cnt      = (unsigned*)alloc((size_t)N * 4);
  unsigned* rowstart = (unsigned*)alloc((size_t)(N + 1) * 4);
  unsigned* wcount   = (unsigned*)alloc((size_t)N * 4);
  unsigned* bsum     = (unsigned*)alloc((size_t)1024);
  uint2*    eb       = (uint2*)alloc((size_t)E * 8);

  const int NB = (N + 1 + 255) / 256;

  init_k<<<(N + 255) / 256, 256, 0, stream>>>(cnt, N);
  gemm_fused<<<(N + 63) / 64, 256, 0, stream>>>(seq, W, a1w, a1b, a2w, a2b, hb, f1, f2, N);
  hist_k<<<(E / 4 + 255) / 256, 256, 0, stream>>>(erow, cnt, E);
  scan_reduce<<<NB, 256, 0, stream>>>(cnt, bsum, N);
  scan_top<<<1, 256, 0, stream>>>(bsum, NB);
  scan_apply<<<NB, 256, 0, stream>>>(cnt, bsum, rowstart, wcount, N);
  scatter_k<<<(E / 4 + 255) / 256, 256, 0, stream>>>(erow, ecol, weight, f1, f2, wcount, eb, E);
  spmm<<<(N * 64 + 255) / 256, 256, 0, stream>>>(rowstart, eb, hb, bias, out, N);
}

// Round 10
// 276.121 us; speedup vs baseline: 1.8831x; 1.0062x over previous
//
#include <hip/hip_runtime.h>
#include <math.h>

#define ALPHA 0.2f

__device__ __forceinline__ unsigned short f2bf(float x) {
  unsigned u = __float_as_uint(x);
  unsigned r = (u + 0x7FFFu + ((u >> 16) & 1u)) >> 16;
  return (unsigned short)r;
}
__device__ __forceinline__ float bf2f(unsigned s) { return __uint_as_float(s << 16); }

// ---------------- init ----------------
__global__ void init_k(unsigned* cnt, int N) {
  int i = blockIdx.x * blockDim.x + threadIdx.x;
  if (i < N) cnt[i] = 0u;
}

// ---------------- GEMM h=seq@W fused with f1/f2 + bf16(h) ----------------
__global__ __launch_bounds__(256) void gemm_fused(
    const float* __restrict__ seq, const float* __restrict__ W,
    const float* __restrict__ a1w, const float* __restrict__ a1b,
    const float* __restrict__ a2w, const float* __restrict__ a2b,
    unsigned* __restrict__ hb, float* __restrict__ f1, float* __restrict__ f2, int N) {
  __shared__ float sA[64][33];
  __shared__ float sW[32][128];
  const int tid = threadIdx.x;
  const int tc = tid & 31, tr = tid >> 5;
  const int rowbase = blockIdx.x * 64;
  float acc[8][4] = {};

  for (int k0 = 0; k0 < 256; k0 += 32) {
    #pragma unroll
    for (int l = 0; l < 2; ++l) {
      int fi = tid + l * 256;
      int r = fi >> 3, kg = fi & 7;
      int gr = rowbase + r; if (gr > N - 1) gr = N - 1;
      float4 v = *reinterpret_cast<const float4*>(seq + (size_t)gr * 256 + k0 + kg * 4);
      sA[r][kg * 4 + 0] = v.x; sA[r][kg * 4 + 1] = v.y;
      sA[r][kg * 4 + 2] = v.z; sA[r][kg * 4 + 3] = v.w;
    }
    #pragma unroll
    for (int l = 0; l < 4; ++l) {
      int fi = tid + l * 256;
      int kk = fi >> 5, cg = fi & 31;
      float4 v = *reinterpret_cast<const float4*>(W + (size_t)(k0 + kk) * 128 + cg * 4);
      *reinterpret_cast<float4*>(&sW[kk][cg * 4]) = v;
    }
    __syncthreads();
    #pragma unroll 4
    for (int kk = 0; kk < 32; ++kk) {
      float b0 = sW[kk][tc * 4 + 0], b1 = sW[kk][tc * 4 + 1];
      float b2 = sW[kk][tc * 4 + 2], b3 = sW[kk][tc * 4 + 3];
      #pragma unroll
      for (int j = 0; j < 8; ++j) {
        float a = sA[tr * 8 + j][kk];
        acc[j][0] += a * b0; acc[j][1] += a * b1;
        acc[j][2] += a * b2; acc[j][3] += a * b3;
      }
    }
    __syncthreads();
  }

  float a1c[4], a2c[4];
  #pragma unroll
  for (int q = 0; q < 4; ++q) { a1c[q] = a1w[tc * 4 + q]; a2c[q] = a2w[tc * 4 + q]; }
  float b1s = a1b[0], b2s = a2b[0];

  #pragma unroll
  for (int j = 0; j < 8; ++j) {
    int gr = rowbase + tr * 8 + j;
    float p1 = acc[j][0] * a1c[0] + acc[j][1] * a1c[1] + acc[j][2] * a1c[2] + acc[j][3] * a1c[3];
    float p2 = acc[j][0] * a2c[0] + acc[j][1] * a2c[1] + acc[j][2] * a2c[2] + acc[j][3] * a2c[3];
    #pragma unroll
    for (int off = 16; off > 0; off >>= 1) {
      p1 += __shfl_xor(p1, off);
      p2 += __shfl_xor(p2, off);
    }
    if (gr < N) {
      unsigned p0 = (unsigned)f2bf(acc[j][0]) | ((unsigned)f2bf(acc[j][1]) << 16);
      unsigned q0 = (unsigned)f2bf(acc[j][2]) | ((unsigned)f2bf(acc[j][3]) << 16);
      uint2 pk; pk.x = p0; pk.y = q0;
      *reinterpret_cast<uint2*>(hb + (size_t)gr * 64 + tc * 2) = pk;
      if (tc == 0) { f1[gr] = p1 + b1s; f2[gr] = p2 + b2s; }
    }
  }
}

// ---------------- histogram: 4 edges/thread ----------------
__global__ void hist_k(const int* __restrict__ row, unsigned* __restrict__ cnt, int E) {
  int t = blockIdx.x * blockDim.x + threadIdx.x;
  int base = t * 4;
  if (base + 3 < E) {
    int4 r = *reinterpret_cast<const int4*>(row + base);
    atomicAdd(&cnt[r.x], 1u);
    atomicAdd(&cnt[r.y], 1u);
    atomicAdd(&cnt[r.z], 1u);
    atomicAdd(&cnt[r.w], 1u);
  } else {
    for (int i = base; i < E; ++i) atomicAdd(&cnt[row[i]], 1u);
  }
}

// ---------------- scan (3-kernel block scan over N+1 entries) ----------------
__global__ __launch_bounds__(256) void scan_reduce(const unsigned* __restrict__ cnt,
                                                   unsigned* __restrict__ bsum, int N) {
  int i = blockIdx.x * 256 + threadIdx.x;
  unsigned v = (i < N) ? cnt[i] : 0u;
  #pragma unroll
  for (int o = 32; o > 0; o >>= 1) v += __shfl_down(v, o);
  __shared__ unsigned ws4[4];
  int lane = threadIdx.x & 63, wid = threadIdx.x >> 6;
  if (lane == 0) ws4[wid] = v;
  __syncthreads();
  if (threadIdx.x == 0) bsum[blockIdx.x] = ws4[0] + ws4[1] + ws4[2] + ws4[3];
}

__global__ __launch_bounds__(256) void scan_top(unsigned* bsum, int nb) {
  __shared__ unsigned ls[256];
  int t = threadIdx.x;
  unsigned x = (t < nb) ? bsum[t] : 0u;
  ls[t] = x;
  __syncthreads();
  for (int off = 1; off < 256; off <<= 1) {
    unsigned y = (t >= off) ? ls[t - off] : 0u;
    __syncthreads();
    ls[t] += y;
    __syncthreads();
  }
  if (t < nb) bsum[t] = ls[t] - x;  // exclusive
}

__global__ __launch_bounds__(256) void scan_apply(const unsigned* __restrict__ cnt,
                                                  const unsigned* __restrict__ boff,
                                                  unsigned* __restrict__ rowstart,
                                                  unsigned* __restrict__ wcount, int N) {
  __shared__ unsigned ls[256];
  int t = threadIdx.x;
  int i = blockIdx.x * 256 + t;
  unsigned x = (i < N) ? cnt[i] : 0u;
  ls[t] = x;
  __syncthreads();
  for (int off = 1; off < 256; off <<= 1) {
    unsigned y = (t >= off) ? ls[t - off] : 0u;
    __syncthreads();
    ls[t] += y;
    __syncthreads();
  }
  unsigned excl = ls[t] - x + boff[blockIdx.x];
  if (i <= N) rowstart[i] = excl;
  if (i < N) wcount[i] = excl;
}

// ---------------- scatter: XCD-binned CSR scatter ----------------
// Rows partitioned into 128-row buckets; bucket -> virtual XCD = (row>>7)&7.
// Block b = (chunk b>>3, vxcd b&7) reads its 1024-edge chunk and commits ONLY
// edges whose bucket matches b&7. Consecutive blockIdx round-robin physical
// XCDs, so each 32KB CSR stripe is written from a single XCD: dirty lines
// accumulate all ~8 writes in that XCD's L2 before eviction (write ~13MB vs
// 103MB), and wcount atomics are XCD-local. Costs 8x edge-stream reads.
// Correctness does NOT depend on the dispatch mapping (filter is symbolic).
#define SCHUNK 1024
__global__ __launch_bounds__(256) void scatter_k(const int* __restrict__ row,
                                                 const int* __restrict__ col,
                                                 const float* __restrict__ w,
                                                 const float* __restrict__ f1,
                                                 const float* __restrict__ f2,
                                                 unsigned* __restrict__ wcount,
                                                 uint2* __restrict__ eb, int E) {
  const int vx = blockIdx.x & 7;
  const int c  = blockIdx.x >> 3;
  const int base = c * SCHUNK + (int)threadIdx.x * 4;
  if (base >= E) return;
  int rr[4], cc[4];
  float ww[4];
  int n;
  if (base + 3 < E) {
    int4 r4 = *reinterpret_cast<const int4*>(row + base);
    int4 c4 = *reinterpret_cast<const int4*>(col + base);
    float4 w4 = *reinterpret_cast<const float4*>(w + base);
    rr[0] = r4.x; rr[1] = r4.y; rr[2] = r4.z; rr[3] = r4.w;
    cc[0] = c4.x; cc[1] = c4.y; cc[2] = c4.z; cc[3] = c4.w;
    ww[0] = w4.x; ww[1] = w4.y; ww[2] = w4.z; ww[3] = w4.w;
    n = 4;
  } else {
    n = E - base;
    for (int i = 0; i < n; ++i) { rr[i] = row[base + i]; cc[i] = col[base + i]; ww[i] = w[base + i]; }
  }
  #pragma unroll
  for (int i = 0; i < 4; ++i) {
    if (i >= n) break;
    int r = rr[i];
    if (((r >> 7) & 7) != vx) continue;
    float x = f1[r] + f2[cc[i]];
    x = x > 0.0f ? x : ALPHA * x;
    x *= ww[i];
    unsigned pos = atomicAdd(&wcount[r], 1u);
    uint2 pk; pk.x = __float_as_uint(x); pk.y = (unsigned)cc[i];
    eb[pos] = pk;
  }
}

// ---------------- fused softmax + pull SpMM ----------------
// One wave per row; 4 quarter-waves (16 lanes x uint4 = 256B) gather 4 edges'
// h-rows simultaneously. eb read ONCE per lane; softmax via shuffles.
// NOTE: inner edge loop must be WAVE-UNIFORM (bk over uniform nloc) so that
// __shfl sources are always active lanes; k<nloc predicates only the gather.
__global__ __launch_bounds__(256) void spmm(const unsigned* __restrict__ rowstart,
                                            const uint2* __restrict__ eb,
                                            const unsigned* __restrict__ hb,
                                            const float* __restrict__ bias,
                                            float* __restrict__ out, int N) {
  int wid = (blockIdx.x * 256 + threadIdx.x) >> 6;
  int lane = threadIdx.x & 63;
  if (wid >= N) return;
  const int s = (int)rowstart[wid], e = (int)rowstart[wid + 1];
  const int qw = lane >> 4;   // quarter id 0..3
  const int ql = lane & 15;   // lane within quarter

  // ---- load chunk 0 into registers (common case: whole row) ----
  int j0 = s + lane;
  float x0 = -3.4e38f;
  int c0 = 0;
  if (j0 < e) {
    uint2 t = eb[j0];
    x0 = __uint_as_float(t.x);
    c0 = (int)t.y;
  }

  // ---- online max/denom across chunks ----
  float cm = x0;
  #pragma unroll
  for (int off = 32; off > 0; off >>= 1) cm = fmaxf(cm, __shfl_xor(cm, off));
  float m = cm;
  float ex = (j0 < e) ? __expf(x0 - m) : 0.0f;
  float cs = ex;
  #pragma unroll
  for (int off = 32; off > 0; off >>= 1) cs += __shfl_xor(cs, off);
  float dsum = cs;
  for (int base = s + 64; base < e; base += 64) {  // rare (>64-edge rows)
    int j = base + lane;
    float x = (j < e) ? __uint_as_float(eb[j].x) : -3.4e38f;
    float c2 = x;
    #pragma unroll
    for (int off = 32; off > 0; off >>= 1) c2 = fmaxf(c2, __shfl_xor(c2, off));
    float mn = fmaxf(m, c2);
    float e2 = (j < e) ? __expf(x - mn) : 0.0f;
    #pragma unroll
    for (int off = 32; off > 0; off >>= 1) e2 += __shfl_xor(e2, off);
    dsum = dsum * __expf(m - mn) + e2;
    m = mn;
  }
  float rd = 1.0f / fmaxf(dsum, 1e-38f);

  // ---- accumulate: quarter qw handles edges k = bk + qw, bk wave-uniform ----
  float acc[8] = {};
  float cf_reg = (j0 < e) ? __expf(x0 - m) * rd : 0.0f;
  int c_reg = c0;
  for (int base = s; base < e; base += 64) {
    if (base != s) {  // reload for rare multi-chunk rows
      int j = base + lane;
      if (j < e) {
        uint2 t = eb[j];
        cf_reg = __expf(__uint_as_float(t.x) - m) * rd;
        c_reg = (int)t.y;
      } else {
        cf_reg = 0.0f; c_reg = 0;
      }
    }
    int nloc = e - base; if (nloc > 64) nloc = 64;
    for (int bk = 0; bk < nloc; bk += 4) {  // wave-uniform trip count
      int k = bk + qw;                       // may exceed nloc by up to 3
      int ksrc = (k < 64) ? k : 0;           // clamp shfl source
      float cfk = __shfl(cf_reg, ksrc);      // full exec mask here
      int ck = __shfl(c_reg, ksrc);
      if (k < nloc) {
        const uint4 hv = *reinterpret_cast<const uint4*>(hb + (size_t)ck * 64 + ql * 4);
        acc[0] += cfk * bf2f(hv.x & 0xFFFFu); acc[1] += cfk * bf2f(hv.x >> 16);
        acc[2] += cfk * bf2f(hv.y & 0xFFFFu); acc[3] += cfk * bf2f(hv.y >> 16);
        acc[4] += cfk * bf2f(hv.z & 0xFFFFu); acc[5] += cfk * bf2f(hv.z >> 16);
        acc[6] += cfk * bf2f(hv.w & 0xFFFFu); acc[7] += cfk * bf2f(hv.w >> 16);
      }
    }
  }

  // ---- cross-quarter reduction: lanes {ql, ql+16, ql+32, ql+48} hold same d-slice ----
  #pragma unroll
  for (int i = 0; i < 8; ++i) {
    acc[i] += __shfl_xor(acc[i], 16);
    acc[i] += __shfl_xor(acc[i], 32);
  }

  if (qw == 0) {
    const int d0 = ql * 8;
    float4 b0 = *reinterpret_cast<const float4*>(bias + d0);
    float4 b1 = *reinterpret_cast<const float4*>(bias + d0 + 4);
    float4 o0, o1;
    o0.x = fmaxf(acc[0] + b0.x, 0.0f); o0.y = fmaxf(acc[1] + b0.y, 0.0f);
    o0.z = fmaxf(acc[2] + b0.z, 0.0f); o0.w = fmaxf(acc[3] + b0.w, 0.0f);
    o1.x = fmaxf(acc[4] + b1.x, 0.0f); o1.y = fmaxf(acc[5] + b1.y, 0.0f);
    o1.z = fmaxf(acc[6] + b1.z, 0.0f); o1.w = fmaxf(acc[7] + b1.w, 0.0f);
    *reinterpret_cast<float4*>(out + (size_t)wid * 128 + d0) = o0;
    *reinterpret_cast<float4*>(out + (size_t)wid * 128 + d0 + 4) = o1;
  }
}

extern "C" void kernel_launch(void* const* d_in, const int* in_sizes, int n_in,
                              void* d_out, int out_size, void* d_ws, size_t ws_size,
                              hipStream_t stream) {
  const float* seq    = (const float*)d_in[0];
  const int*   erow   = (const int*)d_in[1];
  const int*   ecol   = (const int*)d_in[2];
  const float* weight = (const float*)d_in[3];
  const float* W      = (const float*)d_in[4];
  const float* a1w    = (const float*)d_in[5];
  const float* a1b    = (const float*)d_in[6];
  const float* a2w    = (const float*)d_in[7];
  const float* a2b    = (const float*)d_in[8];
  const float* bias   = (const float*)d_in[9];
  const int N = in_sizes[0] / 256;
  const int E = in_sizes[1];
  float* out = (float*)d_out;

  char* p = (char*)d_ws;
  auto alloc = [&](size_t bytes) -> char* {
    char* q = p;
    p += (bytes + 255) & ~(size_t)255;
    return q;
  };
  unsigned* hb       = (unsigned*)alloc((size_t)N * 64 * 4);
  float*    f1       = (float*)alloc((size_t)N * 4);
  float*    f2       = (float*)alloc((size_t)N * 4);
  unsigned* cnt      = (unsigned*)alloc((size_t)N * 4);
  unsigned* rowstart = (unsigned*)alloc((size_t)(N + 1) * 4);
  unsigned* wcount   = (unsigned*)alloc((size_t)N * 4);
  unsigned* bsum     = (unsigned*)alloc((size_t)1024);
  uint2*    eb       = (uint2*)alloc((size_t)E * 8);

  const int NB = (N + 1 + 255) / 256;

  init_k<<<(N + 255) / 256, 256, 0, stream>>>(cnt, N);
  gemm_fused<<<(N + 63) / 64, 256, 0, stream>>>(seq, W, a1w, a1b, a2w, a2b, hb, f1, f2, N);
  hist_k<<<(E / 4 + 255) / 256, 256, 0, stream>>>(erow, cnt, E);
  scan_reduce<<<NB, 256, 0, stream>>>(cnt, bsum, N);
  scan_top<<<1, 256, 0, stream>>>(bsum, NB);
  scan_apply<<<NB, 256, 0, stream>>>(cnt, bsum, rowstart, wcount, N);
  scatter_k<<<8 * ((E + SCHUNK - 1) / SCHUNK), 256, 0, stream>>>(erow, ecol, weight, f1, f2, wcount, eb, E);
  spmm<<<(N * 64 + 255) / 256, 256, 0, stream>>>(rowstart, eb, hb, bias, out, N);
}

// Round 11
// 240.785 us; speedup vs baseline: 2.1595x; 1.1468x over previous
//
#include <hip/hip_runtime.h>
#include <math.h>

#define ALPHA 0.2f
#define BKT 128      // rows per bucket
#define PCHUNK 4096  // edges per binA block

__device__ __forceinline__ unsigned short f2bf(float x) {
  unsigned u = __float_as_uint(x);
  unsigned r = (u + 0x7FFFu + ((u >> 16) & 1u)) >> 16;
  return (unsigned short)r;
}
__device__ __forceinline__ float bf2f(unsigned s) { return __uint_as_float(s << 16); }

// ---------------- init ----------------
__global__ void init_k(unsigned* cnt, int N) {
  int i = blockIdx.x * blockDim.x + threadIdx.x;
  if (i < N) cnt[i] = 0u;
}

__global__ void init_tail(const unsigned* __restrict__ rowstart, unsigned* __restrict__ tail,
                          int NBKT, int N) {
  int b = blockIdx.x * blockDim.x + threadIdx.x;
  if (b < NBKT) {
    int r = b * BKT; if (r > N) r = N;
    tail[b] = rowstart[r];
  }
}

// ---------------- GEMM h=seq@W fused with f1/f2 + bf16(h) ----------------
__global__ __launch_bounds__(256) void gemm_fused(
    const float* __restrict__ seq, const float* __restrict__ W,
    const float* __restrict__ a1w, const float* __restrict__ a1b,
    const float* __restrict__ a2w, const float* __restrict__ a2b,
    unsigned* __restrict__ hb, float* __restrict__ f1, float* __restrict__ f2, int N) {
  __shared__ float sA[64][33];
  __shared__ float sW[32][128];
  const int tid = threadIdx.x;
  const int tc = tid & 31, tr = tid >> 5;
  const int rowbase = blockIdx.x * 64;
  float acc[8][4] = {};

  for (int k0 = 0; k0 < 256; k0 += 32) {
    #pragma unroll
    for (int l = 0; l < 2; ++l) {
      int fi = tid + l * 256;
      int r = fi >> 3, kg = fi & 7;
      int gr = rowbase + r; if (gr > N - 1) gr = N - 1;
      float4 v = *reinterpret_cast<const float4*>(seq + (size_t)gr * 256 + k0 + kg * 4);
      sA[r][kg * 4 + 0] = v.x; sA[r][kg * 4 + 1] = v.y;
      sA[r][kg * 4 + 2] = v.z; sA[r][kg * 4 + 3] = v.w;
    }
    #pragma unroll
    for (int l = 0; l < 4; ++l) {
      int fi = tid + l * 256;
      int kk = fi >> 5, cg = fi & 31;
      float4 v = *reinterpret_cast<const float4*>(W + (size_t)(k0 + kk) * 128 + cg * 4);
      *reinterpret_cast<float4*>(&sW[kk][cg * 4]) = v;
    }
    __syncthreads();
    #pragma unroll 4
    for (int kk = 0; kk < 32; ++kk) {
      float b0 = sW[kk][tc * 4 + 0], b1 = sW[kk][tc * 4 + 1];
      float b2 = sW[kk][tc * 4 + 2], b3 = sW[kk][tc * 4 + 3];
      #pragma unroll
      for (int j = 0; j < 8; ++j) {
        float a = sA[tr * 8 + j][kk];
        acc[j][0] += a * b0; acc[j][1] += a * b1;
        acc[j][2] += a * b2; acc[j][3] += a * b3;
      }
    }
    __syncthreads();
  }

  float a1c[4], a2c[4];
  #pragma unroll
  for (int q = 0; q < 4; ++q) { a1c[q] = a1w[tc * 4 + q]; a2c[q] = a2w[tc * 4 + q]; }
  float b1s = a1b[0], b2s = a2b[0];

  #pragma unroll
  for (int j = 0; j < 8; ++j) {
    int gr = rowbase + tr * 8 + j;
    float p1 = acc[j][0] * a1c[0] + acc[j][1] * a1c[1] + acc[j][2] * a1c[2] + acc[j][3] * a1c[3];
    float p2 = acc[j][0] * a2c[0] + acc[j][1] * a2c[1] + acc[j][2] * a2c[2] + acc[j][3] * a2c[3];
    #pragma unroll
    for (int off = 16; off > 0; off >>= 1) {
      p1 += __shfl_xor(p1, off);
      p2 += __shfl_xor(p2, off);
    }
    if (gr < N) {
      unsigned p0 = (unsigned)f2bf(acc[j][0]) | ((unsigned)f2bf(acc[j][1]) << 16);
      unsigned q0 = (unsigned)f2bf(acc[j][2]) | ((unsigned)f2bf(acc[j][3]) << 16);
      uint2 pk; pk.x = p0; pk.y = q0;
      *reinterpret_cast<uint2*>(hb + (size_t)gr * 64 + tc * 2) = pk;
      if (tc == 0) { f1[gr] = p1 + b1s; f2[gr] = p2 + b2s; }
    }
  }
}

// ---------------- histogram: 4 edges/thread ----------------
__global__ void hist_k(const int* __restrict__ row, unsigned* __restrict__ cnt, int E) {
  int t = blockIdx.x * blockDim.x + threadIdx.x;
  int base = t * 4;
  if (base + 3 < E) {
    int4 r = *reinterpret_cast<const int4*>(row + base);
    atomicAdd(&cnt[r.x], 1u);
    atomicAdd(&cnt[r.y], 1u);
    atomicAdd(&cnt[r.z], 1u);
    atomicAdd(&cnt[r.w], 1u);
  } else {
    for (int i = base; i < E; ++i) atomicAdd(&cnt[row[i]], 1u);
  }
}

// ---------------- scan (3-kernel block scan over N+1 entries) ----------------
__global__ __launch_bounds__(256) void scan_reduce(const unsigned* __restrict__ cnt,
                                                   unsigned* __restrict__ bsum, int N) {
  int i = blockIdx.x * 256 + threadIdx.x;
  unsigned v = (i < N) ? cnt[i] : 0u;
  #pragma unroll
  for (int o = 32; o > 0; o >>= 1) v += __shfl_down(v, o);
  __shared__ unsigned ws4[4];
  int lane = threadIdx.x & 63, wid = threadIdx.x >> 6;
  if (lane == 0) ws4[wid] = v;
  __syncthreads();
  if (threadIdx.x == 0) bsum[blockIdx.x] = ws4[0] + ws4[1] + ws4[2] + ws4[3];
}

__global__ __launch_bounds__(256) void scan_top(unsigned* bsum, int nb) {
  __shared__ unsigned ls[256];
  int t = threadIdx.x;
  unsigned x = (t < nb) ? bsum[t] : 0u;
  ls[t] = x;
  __syncthreads();
  for (int off = 1; off < 256; off <<= 1) {
    unsigned y = (t >= off) ? ls[t - off] : 0u;
    __syncthreads();
    ls[t] += y;
    __syncthreads();
  }
  if (t < nb) bsum[t] = ls[t] - x;  // exclusive
}

__global__ __launch_bounds__(256) void scan_apply(const unsigned* __restrict__ cnt,
                                                  const unsigned* __restrict__ boff,
                                                  unsigned* __restrict__ rowstart, int N) {
  __shared__ unsigned ls[256];
  int t = threadIdx.x;
  int i = blockIdx.x * 256 + t;
  unsigned x = (i < N) ? cnt[i] : 0u;
  ls[t] = x;
  __syncthreads();
  for (int off = 1; off < 256; off <<= 1) {
    unsigned y = (t >= off) ? ls[t - off] : 0u;
    __syncthreads();
    ls[t] += y;
    __syncthreads();
  }
  unsigned excl = ls[t] - x + boff[blockIdx.x];
  if (i <= N) rowstart[i] = excl;
}

// ---------------- Pass A: LDS radix binning into row-buckets ----------------
// Each block: 4096 edges -> compute v -> bin by bucket b=r>>7 in LDS (count,
// wave-shfl prefix scan, place) -> reserve contiguous global range per bucket
// (one atomic each) -> flush bucket-sorted runs coalesced to staging.
// pk packs (c<<16)|r  (both < 65536); bucket/rlocal derived from r bits.
__global__ __launch_bounds__(256) void binA(const int* __restrict__ row,
                                            const int* __restrict__ col,
                                            const float* __restrict__ w,
                                            const float* __restrict__ f1,
                                            const float* __restrict__ f2,
                                            unsigned* __restrict__ tail,
                                            uint2* __restrict__ stg, int E, int NBKT) {
  __shared__ unsigned bcnt[512];
  __shared__ unsigned bcur[512];
  __shared__ uint2 sstg[PCHUNK];
  const int tid = threadIdx.x;
  const int lane = tid & 63, wv = tid >> 6;
  const int base = blockIdx.x * PCHUNK;

  for (int i = tid; i < 512; i += 256) bcnt[i] = 0u;
  __syncthreads();

  // load + compute v + count
  float vv[16];
  unsigned pk[16];
  #pragma unroll
  for (int l = 0; l < 16; ++l) {
    int idx = base + tid + l * 256;
    if (idx < E) {
      int r = row[idx], c = col[idx];
      float x = f1[r] + f2[c];
      x = x > 0.0f ? x : ALPHA * x;
      x *= w[idx];
      vv[l] = x;
      pk[l] = ((unsigned)c << 16) | (unsigned)r;
      atomicAdd(&bcnt[r >> 7], 1u);
    } else {
      pk[l] = 0xFFFFFFFFu;
    }
  }
  __syncthreads();

  // exclusive prefix scan over 512 bucket counts (2 slots/thread + wave shfl)
  unsigned a0 = bcnt[2 * tid], a1 = bcnt[2 * tid + 1];
  unsigned pairv = a0 + a1;
  unsigned x = pairv;
  #pragma unroll
  for (int d = 1; d < 64; d <<= 1) {
    unsigned y = __shfl_up(x, d);
    if (lane >= d) x += y;
  }
  __shared__ unsigned wsum[4];
  if (lane == 63) wsum[wv] = x;
  __syncthreads();
  unsigned woff = 0;
  for (int i = 0; i < wv; ++i) woff += wsum[i];
  unsigned exclp = x + woff - pairv;
  bcur[2 * tid] = exclp;
  bcur[2 * tid + 1] = exclp + a0;
  __syncthreads();

  // place into LDS staging (bucket-grouped)
  #pragma unroll
  for (int l = 0; l < 16; ++l) {
    if (pk[l] != 0xFFFFFFFFu) {
      unsigned b = (pk[l] & 0xFFFFu) >> 7;
      unsigned p = atomicAdd(&bcur[b], 1u);
      sstg[p] = make_uint2(__float_as_uint(vv[l]), pk[l]);
    }
  }
  __syncthreads();

  // reserve global ranges; store delta in bcnt
  for (int b = tid; b < NBKT; b += 256) {
    unsigned c = bcnt[b];
    if (c) {
      unsigned g = atomicAdd(&tail[b], c);
      bcnt[b] = g - (bcur[b] - c);  // delta = globalstart - ldsstart
    }
  }
  __syncthreads();

  // coalesced flush: staging slot i -> stg[i + delta[bucket]]
  int ne = E - base; if (ne > PCHUNK) ne = PCHUNK;
  for (int i = tid; i < ne; i += 256) {
    uint2 e2 = sstg[i];
    unsigned b = (e2.y & 0xFFFFu) >> 7;
    stg[i + bcnt[b]] = e2;
  }
}

// ---------------- Pass B: bucket -> exact CSR slots (L2-local window) ----------------
__global__ __launch_bounds__(256) void binB(const unsigned* __restrict__ rowstart,
                                            const uint2* __restrict__ stg,
                                            uint2* __restrict__ eb, int N) {
  const int b = blockIdx.x;
  const int r0 = b * BKT;
  int r1 = r0 + BKT; if (r1 > N) r1 = N;
  __shared__ unsigned cur[BKT];
  for (int i = threadIdx.x; i < r1 - r0; i += 256) cur[i] = rowstart[r0 + i];
  __syncthreads();
  const int sA = (int)rowstart[r0], eA = (int)rowstart[r1];
  for (int i = sA + (int)threadIdx.x; i < eA; i += 256) {
    uint2 e2 = stg[i];
    unsigned rl = e2.y & 127u;
    unsigned c = e2.y >> 16;
    unsigned slot = atomicAdd(&cur[rl], 1u);
    eb[slot] = make_uint2(e2.x, c);
  }
}

// ---------------- fused softmax + pull SpMM ----------------
// One wave per row; 4 quarter-waves (16 lanes x uint4 = 256B) gather 4 edges'
// h-rows simultaneously. eb read ONCE per lane; softmax via shuffles.
// Inner edge loop is WAVE-UNIFORM so __shfl sources are always active lanes.
__global__ __launch_bounds__(256) void spmm(const unsigned* __restrict__ rowstart,
                                            const uint2* __restrict__ eb,
                                            const unsigned* __restrict__ hb,
                                            const float* __restrict__ bias,
                                            float* __restrict__ out, int N) {
  int wid = (blockIdx.x * 256 + threadIdx.x) >> 6;
  int lane = threadIdx.x & 63;
  if (wid >= N) return;
  const int s = (int)rowstart[wid], e = (int)rowstart[wid + 1];
  const int qw = lane >> 4;
  const int ql = lane & 15;

  int j0 = s + lane;
  float x0 = -3.4e38f;
  int c0 = 0;
  if (j0 < e) {
    uint2 t = eb[j0];
    x0 = __uint_as_float(t.x);
    c0 = (int)t.y;
  }

  float cm = x0;
  #pragma unroll
  for (int off = 32; off > 0; off >>= 1) cm = fmaxf(cm, __shfl_xor(cm, off));
  float m = cm;
  float ex = (j0 < e) ? __expf(x0 - m) : 0.0f;
  float cs = ex;
  #pragma unroll
  for (int off = 32; off > 0; off >>= 1) cs += __shfl_xor(cs, off);
  float dsum = cs;
  for (int base = s + 64; base < e; base += 64) {
    int j = base + lane;
    float x = (j < e) ? __uint_as_float(eb[j].x) : -3.4e38f;
    float c2 = x;
    #pragma unroll
    for (int off = 32; off > 0; off >>= 1) c2 = fmaxf(c2, __shfl_xor(c2, off));
    float mn = fmaxf(m, c2);
    float e2 = (j < e) ? __expf(x - mn) : 0.0f;
    #pragma unroll
    for (int off = 32; off > 0; off >>= 1) e2 += __shfl_xor(e2, off);
    dsum = dsum * __expf(m - mn) + e2;
    m = mn;
  }
  float rd = 1.0f / fmaxf(dsum, 1e-38f);

  float acc[8] = {};
  float cf_reg = (j0 < e) ? __expf(x0 - m) * rd : 0.0f;
  int c_reg = c0;
  for (int base = s; base < e; base += 64) {
    if (base != s) {
      int j = base + lane;
      if (j < e) {
        uint2 t = eb[j];
        cf_reg = __expf(__uint_as_float(t.x) - m) * rd;
        c_reg = (int)t.y;
      } else {
        cf_reg = 0.0f; c_reg = 0;
      }
    }
    int nloc = e - base; if (nloc > 64) nloc = 64;
    for (int bk = 0; bk < nloc; bk += 4) {
      int k = bk + qw;
      int ksrc = (k < 64) ? k : 0;
      float cfk = __shfl(cf_reg, ksrc);
      int ck = __shfl(c_reg, ksrc);
      if (k < nloc) {
        const uint4 hv = *reinterpret_cast<const uint4*>(hb + (size_t)ck * 64 + ql * 4);
        acc[0] += cfk * bf2f(hv.x & 0xFFFFu); acc[1] += cfk * bf2f(hv.x >> 16);
        acc[2] += cfk * bf2f(hv.y & 0xFFFFu); acc[3] += cfk * bf2f(hv.y >> 16);
        acc[4] += cfk * bf2f(hv.z & 0xFFFFu); acc[5] += cfk * bf2f(hv.z >> 16);
        acc[6] += cfk * bf2f(hv.w & 0xFFFFu); acc[7] += cfk * bf2f(hv.w >> 16);
      }
    }
  }

  #pragma unroll
  for (int i = 0; i < 8; ++i) {
    acc[i] += __shfl_xor(acc[i], 16);
    acc[i] += __shfl_xor(acc[i], 32);
  }

  if (qw == 0) {
    const int d0 = ql * 8;
    float4 b0 = *reinterpret_cast<const float4*>(bias + d0);
    float4 b1 = *reinterpret_cast<const float4*>(bias + d0 + 4);
    float4 o0, o1;
    o0.x = fmaxf(acc[0] + b0.x, 0.0f); o0.y = fmaxf(acc[1] + b0.y, 0.0f);
    o0.z = fmaxf(acc[2] + b0.z, 0.0f); o0.w = fmaxf(acc[3] + b0.w, 0.0f);
    o1.x = fmaxf(acc[4] + b1.x, 0.0f); o1.y = fmaxf(acc[5] + b1.y, 0.0f);
    o1.z = fmaxf(acc[6] + b1.z, 0.0f); o1.w = fmaxf(acc[7] + b1.w, 0.0f);
    *reinterpret_cast<float4*>(out + (size_t)wid * 128 + d0) = o0;
    *reinterpret_cast<float4*>(out + (size_t)wid * 128 + d0 + 4) = o1;
  }
}

extern "C" void kernel_launch(void* const* d_in, const int* in_sizes, int n_in,
                              void* d_out, int out_size, void* d_ws, size_t ws_size,
                              hipStream_t stream) {
  const float* seq    = (const float*)d_in[0];
  const int*   erow   = (const int*)d_in[1];
  const int*   ecol   = (const int*)d_in[2];
  const float* weight = (const float*)d_in[3];
  const float* W      = (const float*)d_in[4];
  const float* a1w    = (const float*)d_in[5];
  const float* a1b    = (const float*)d_in[6];
  const float* a2w    = (const float*)d_in[7];
  const float* a2b    = (const float*)d_in[8];
  const float* bias   = (const float*)d_in[9];
  const int N = in_sizes[0] / 256;
  const int E = in_sizes[1];
  float* out = (float*)d_out;

  char* p = (char*)d_ws;
  auto alloc = [&](size_t bytes) -> char* {
    char* q = p;
    p += (bytes + 255) & ~(size_t)255;
    return q;
  };
  unsigned* hb       = (unsigned*)alloc((size_t)N * 64 * 4);
  float*    f1       = (float*)alloc((size_t)N * 4);
  float*    f2       = (float*)alloc((size_t)N * 4);
  unsigned* cnt      = (unsigned*)alloc((size_t)N * 4);
  unsigned* rowstart = (unsigned*)alloc((size_t)(N + 1) * 4);
  unsigned* bsum     = (unsigned*)alloc((size_t)1024);
  const int NBKT = (N + BKT - 1) / BKT;
  unsigned* tail     = (unsigned*)alloc((size_t)NBKT * 4);
  uint2*    stg      = (uint2*)alloc((size_t)E * 8);
  uint2*    eb       = (uint2*)alloc((size_t)E * 8);

  const int NB = (N + 1 + 255) / 256;

  init_k<<<(N + 255) / 256, 256, 0, stream>>>(cnt, N);
  gemm_fused<<<(N + 63) / 64, 256, 0, stream>>>(seq, W, a1w, a1b, a2w, a2b, hb, f1, f2, N);
  hist_k<<<(E / 4 + 255) / 256, 256, 0, stream>>>(erow, cnt, E);
  scan_reduce<<<NB, 256, 0, stream>>>(cnt, bsum, N);
  scan_top<<<1, 256, 0, stream>>>(bsum, NB);
  scan_apply<<<NB, 256, 0, stream>>>(cnt, bsum, rowstart, N);
  init_tail<<<(NBKT + 255) / 256, 256, 0, stream>>>(rowstart, tail, NBKT, N);
  binA<<<(E + PCHUNK - 1) / PCHUNK, 256, 0, stream>>>(erow, ecol, weight, f1, f2, tail, stg, E, NBKT);
  binB<<<NBKT, 256, 0, stream>>>(rowstart, stg, eb, N);
  spmm<<<(N * 64 + 255) / 256, 256, 0, stream>>>(rowstart, eb, hb, bias, out, N);
}

// Round 12
// 199.187 us; speedup vs baseline: 2.6105x; 1.2088x over previous
//
#include <hip/hip_runtime.h>
#include <math.h>

#define ALPHA 0.2f
#define BKT 128      // rows per bucket
#define PCHUNK 4096  // edges per binA block

__device__ __forceinline__ unsigned short f2bf(float x) {
  unsigned u = __float_as_uint(x);
  unsigned r = (u + 0x7FFFu + ((u >> 16) & 1u)) >> 16;
  return (unsigned short)r;
}
__device__ __forceinline__ float bf2f(unsigned s) { return __uint_as_float(s << 16); }

// ---------------- zero bucket counters ----------------
__global__ void init_b(unsigned* bcnt, int n) {
  int i = blockIdx.x * blockDim.x + threadIdx.x;
  if (i < n) bcnt[i] = 0u;
}

// ---------------- GEMM h=seq@W fused with f1/f2 + bf16(h) ----------------
__global__ __launch_bounds__(256) void gemm_fused(
    const float* __restrict__ seq, const float* __restrict__ W,
    const float* __restrict__ a1w, const float* __restrict__ a1b,
    const float* __restrict__ a2w, const float* __restrict__ a2b,
    unsigned* __restrict__ hb, float* __restrict__ f1, float* __restrict__ f2, int N) {
  __shared__ float sA[64][33];
  __shared__ float sW[32][128];
  const int tid = threadIdx.x;
  const int tc = tid & 31, tr = tid >> 5;
  const int rowbase = blockIdx.x * 64;
  float acc[8][4] = {};

  for (int k0 = 0; k0 < 256; k0 += 32) {
    #pragma unroll
    for (int l = 0; l < 2; ++l) {
      int fi = tid + l * 256;
      int r = fi >> 3, kg = fi & 7;
      int gr = rowbase + r; if (gr > N - 1) gr = N - 1;
      float4 v = *reinterpret_cast<const float4*>(seq + (size_t)gr * 256 + k0 + kg * 4);
      sA[r][kg * 4 + 0] = v.x; sA[r][kg * 4 + 1] = v.y;
      sA[r][kg * 4 + 2] = v.z; sA[r][kg * 4 + 3] = v.w;
    }
    #pragma unroll
    for (int l = 0; l < 4; ++l) {
      int fi = tid + l * 256;
      int kk = fi >> 5, cg = fi & 31;
      float4 v = *reinterpret_cast<const float4*>(W + (size_t)(k0 + kk) * 128 + cg * 4);
      *reinterpret_cast<float4*>(&sW[kk][cg * 4]) = v;
    }
    __syncthreads();
    #pragma unroll 4
    for (int kk = 0; kk < 32; ++kk) {
      float b0 = sW[kk][tc * 4 + 0], b1 = sW[kk][tc * 4 + 1];
      float b2 = sW[kk][tc * 4 + 2], b3 = sW[kk][tc * 4 + 3];
      #pragma unroll
      for (int j = 0; j < 8; ++j) {
        float a = sA[tr * 8 + j][kk];
        acc[j][0] += a * b0; acc[j][1] += a * b1;
        acc[j][2] += a * b2; acc[j][3] += a * b3;
      }
    }
    __syncthreads();
  }

  float a1c[4], a2c[4];
  #pragma unroll
  for (int q = 0; q < 4; ++q) { a1c[q] = a1w[tc * 4 + q]; a2c[q] = a2w[tc * 4 + q]; }
  float b1s = a1b[0], b2s = a2b[0];

  #pragma unroll
  for (int j = 0; j < 8; ++j) {
    int gr = rowbase + tr * 8 + j;
    float p1 = acc[j][0] * a1c[0] + acc[j][1] * a1c[1] + acc[j][2] * a1c[2] + acc[j][3] * a1c[3];
    float p2 = acc[j][0] * a2c[0] + acc[j][1] * a2c[1] + acc[j][2] * a2c[2] + acc[j][3] * a2c[3];
    #pragma unroll
    for (int off = 16; off > 0; off >>= 1) {
      p1 += __shfl_xor(p1, off);
      p2 += __shfl_xor(p2, off);
    }
    if (gr < N) {
      unsigned p0 = (unsigned)f2bf(acc[j][0]) | ((unsigned)f2bf(acc[j][1]) << 16);
      unsigned q0 = (unsigned)f2bf(acc[j][2]) | ((unsigned)f2bf(acc[j][3]) << 16);
      uint2 pk; pk.x = p0; pk.y = q0;
      *reinterpret_cast<uint2*>(hb + (size_t)gr * 64 + tc * 2) = pk;
      if (tc == 0) { f1[gr] = p1 + b1s; f2[gr] = p2 + b2s; }
    }
  }
}

// ---------------- bucket histogram: LDS-aggregated ----------------
__global__ __launch_bounds__(256) void bhist(const int* __restrict__ row,
                                             unsigned* __restrict__ bcnt_g, int E, int NBKT) {
  __shared__ unsigned h[512];
  const int tid = threadIdx.x;
  for (int i = tid; i < 512; i += 256) h[i] = 0u;
  __syncthreads();
  int base = (blockIdx.x * 256 + tid) * 4;
  if (base + 3 < E) {
    int4 r = *reinterpret_cast<const int4*>(row + base);
    atomicAdd(&h[r.x >> 7], 1u);
    atomicAdd(&h[r.y >> 7], 1u);
    atomicAdd(&h[r.z >> 7], 1u);
    atomicAdd(&h[r.w >> 7], 1u);
  } else {
    for (int i = base; i < E; ++i) atomicAdd(&h[row[i] >> 7], 1u);
  }
  __syncthreads();
  for (int b = tid; b < NBKT; b += 256) {
    unsigned c = h[b];
    if (c) atomicAdd(&bcnt_g[b], c);
  }
}

// ---------------- bucket scan: 1 block; bstart + tail ----------------
__global__ __launch_bounds__(256) void bscan(const unsigned* __restrict__ bcnt,
                                             unsigned* __restrict__ bstart,
                                             unsigned* __restrict__ tail, int NBKT) {
  __shared__ unsigned wsum[4];
  const int tid = threadIdx.x;
  const int lane = tid & 63, wv = tid >> 6;
  unsigned a0 = (2 * tid < NBKT) ? bcnt[2 * tid] : 0u;
  unsigned a1 = (2 * tid + 1 < NBKT) ? bcnt[2 * tid + 1] : 0u;
  unsigned pairv = a0 + a1;
  unsigned x = pairv;
  #pragma unroll
  for (int d = 1; d < 64; d <<= 1) {
    unsigned y = __shfl_up(x, d);
    if (lane >= d) x += y;
  }
  if (lane == 63) wsum[wv] = x;
  __syncthreads();
  unsigned woff = 0;
  for (int i = 0; i < wv; ++i) woff += wsum[i];
  unsigned exclp = x + woff - pairv;  // exclusive prefix of pair
  if (2 * tid < NBKT)     { bstart[2 * tid] = exclp;       tail[2 * tid] = exclp; }
  if (2 * tid + 1 < NBKT) { bstart[2 * tid + 1] = exclp + a0; tail[2 * tid + 1] = exclp + a0; }
  if (tid == 255) bstart[NBKT] = woff + wsum[3];  // total = E
}

// ---------------- Pass A: LDS radix binning into row-buckets ----------------
__global__ __launch_bounds__(256) void binA(const int* __restrict__ row,
                                            const int* __restrict__ col,
                                            const float* __restrict__ w,
                                            const float* __restrict__ f1,
                                            const float* __restrict__ f2,
                                            unsigned* __restrict__ tail,
                                            uint2* __restrict__ stg, int E, int NBKT) {
  __shared__ unsigned bcnt[512];
  __shared__ unsigned bcur[512];
  __shared__ uint2 sstg[PCHUNK];
  const int tid = threadIdx.x;
  const int lane = tid & 63, wv = tid >> 6;
  const int base = blockIdx.x * PCHUNK;

  for (int i = tid; i < 512; i += 256) bcnt[i] = 0u;
  __syncthreads();

  float vv[16];
  unsigned pk[16];
  #pragma unroll
  for (int l = 0; l < 16; ++l) {
    int idx = base + tid + l * 256;
    if (idx < E) {
      int r = row[idx], c = col[idx];
      float x = f1[r] + f2[c];
      x = x > 0.0f ? x : ALPHA * x;
      x *= w[idx];
      vv[l] = x;
      pk[l] = ((unsigned)c << 16) | (unsigned)r;
      atomicAdd(&bcnt[r >> 7], 1u);
    } else {
      pk[l] = 0xFFFFFFFFu;
    }
  }
  __syncthreads();

  unsigned a0 = bcnt[2 * tid], a1 = bcnt[2 * tid + 1];
  unsigned pairv = a0 + a1;
  unsigned x = pairv;
  #pragma unroll
  for (int d = 1; d < 64; d <<= 1) {
    unsigned y = __shfl_up(x, d);
    if (lane >= d) x += y;
  }
  __shared__ unsigned wsum[4];
  if (lane == 63) wsum[wv] = x;
  __syncthreads();
  unsigned woff = 0;
  for (int i = 0; i < wv; ++i) woff += wsum[i];
  unsigned exclp = x + woff - pairv;
  bcur[2 * tid] = exclp;
  bcur[2 * tid + 1] = exclp + a0;
  __syncthreads();

  #pragma unroll
  for (int l = 0; l < 16; ++l) {
    if (pk[l] != 0xFFFFFFFFu) {
      unsigned b = (pk[l] & 0xFFFFu) >> 7;
      unsigned p = atomicAdd(&bcur[b], 1u);
      sstg[p] = make_uint2(__float_as_uint(vv[l]), pk[l]);
    }
  }
  __syncthreads();

  for (int b = tid; b < NBKT; b += 256) {
    unsigned c = bcnt[b];
    if (c) {
      unsigned g = atomicAdd(&tail[b], c);
      bcnt[b] = g - (bcur[b] - c);  // delta = globalstart - ldsstart
    }
  }
  __syncthreads();

  int ne = E - base; if (ne > PCHUNK) ne = PCHUNK;
  for (int i = tid; i < ne; i += 256) {
    uint2 e2 = sstg[i];
    unsigned b = (e2.y & 0xFFFFu) >> 7;
    stg[i + bcnt[b]] = e2;
  }
}

// ---------------- Pass B: per-row count+scan -> rowstart; place into CSR ----------------
__global__ __launch_bounds__(256) void binB(const unsigned* __restrict__ bstart,
                                            const uint2* __restrict__ stg,
                                            uint2* __restrict__ eb,
                                            unsigned* __restrict__ rowstart, int N, int NBKT) {
  const int b = blockIdx.x;
  const int r0 = b * BKT;
  int r1 = r0 + BKT; if (r1 > N) r1 = N;
  const int nrows = r1 - r0;
  __shared__ unsigned cnt[BKT];
  __shared__ unsigned cur[BKT];
  const int tid = threadIdx.x;
  if (tid < BKT) cnt[tid] = 0u;
  __syncthreads();
  const int sA = (int)bstart[b], eA = (int)bstart[b + 1];

  // pass 1: per-row counts (LDS atomics on cache-hot staged bucket)
  for (int i = sA + tid; i < eA; i += 256) {
    atomicAdd(&cnt[stg[i].y & 127u], 1u);
  }
  __syncthreads();

  // inclusive Hillis-Steele scan over cnt[0..127]
  unsigned orig = (tid < BKT) ? cnt[tid] : 0u;
  for (int off = 1; off < BKT; off <<= 1) {
    unsigned v = 0u;
    if (tid < BKT && tid >= off) v = cnt[tid - off];
    __syncthreads();
    if (tid < BKT) cnt[tid] += v;
    __syncthreads();
  }
  if (tid < nrows) {
    unsigned start = (unsigned)sA + cnt[tid] - orig;  // exclusive
    cur[tid] = start;
    rowstart[r0 + tid] = start;
  }
  if (b == NBKT - 1 && tid == 0) rowstart[N] = (unsigned)eA;
  __syncthreads();

  // pass 2: place into exact CSR slots
  for (int i = sA + tid; i < eA; i += 256) {
    uint2 e2 = stg[i];
    unsigned rl = e2.y & 127u;
    unsigned c = e2.y >> 16;
    unsigned slot = atomicAdd(&cur[rl], 1u);
    eb[slot] = make_uint2(e2.x, c);
  }
}

// ---------------- fused softmax + pull SpMM ----------------
// One wave per row; 4 quarter-waves (16 lanes x uint4 = 256B) gather 4 edges'
// h-rows simultaneously. eb read ONCE per lane; softmax via shuffles.
// Inner edge loop is WAVE-UNIFORM so __shfl sources are always active lanes.
__global__ __launch_bounds__(256) void spmm(const unsigned* __restrict__ rowstart,
                                            const uint2* __restrict__ eb,
                                            const unsigned* __restrict__ hb,
                                            const float* __restrict__ bias,
                                            float* __restrict__ out, int N) {
  int wid = (blockIdx.x * 256 + threadIdx.x) >> 6;
  int lane = threadIdx.x & 63;
  if (wid >= N) return;
  const int s = (int)rowstart[wid], e = (int)rowstart[wid + 1];
  const int qw = lane >> 4;
  const int ql = lane & 15;

  int j0 = s + lane;
  float x0 = -3.4e38f;
  int c0 = 0;
  if (j0 < e) {
    uint2 t = eb[j0];
    x0 = __uint_as_float(t.x);
    c0 = (int)t.y;
  }

  float cm = x0;
  #pragma unroll
  for (int off = 32; off > 0; off >>= 1) cm = fmaxf(cm, __shfl_xor(cm, off));
  float m = cm;
  float ex = (j0 < e) ? __expf(x0 - m) : 0.0f;
  float cs = ex;
  #pragma unroll
  for (int off = 32; off > 0; off >>= 1) cs += __shfl_xor(cs, off);
  float dsum = cs;
  for (int base = s + 64; base < e; base += 64) {
    int j = base + lane;
    float x = (j < e) ? __uint_as_float(eb[j].x) : -3.4e38f;
    float c2 = x;
    #pragma unroll
    for (int off = 32; off > 0; off >>= 1) c2 = fmaxf(c2, __shfl_xor(c2, off));
    float mn = fmaxf(m, c2);
    float e2 = (j < e) ? __expf(x - mn) : 0.0f;
    #pragma unroll
    for (int off = 32; off > 0; off >>= 1) e2 += __shfl_xor(e2, off);
    dsum = dsum * __expf(m - mn) + e2;
    m = mn;
  }
  float rd = 1.0f / fmaxf(dsum, 1e-38f);

  float acc[8] = {};
  float cf_reg = (j0 < e) ? __expf(x0 - m) * rd : 0.0f;
  int c_reg = c0;
  for (int base = s; base < e; base += 64) {
    if (base != s) {
      int j = base + lane;
      if (j < e) {
        uint2 t = eb[j];
        cf_reg = __expf(__uint_as_float(t.x) - m) * rd;
        c_reg = (int)t.y;
      } else {
        cf_reg = 0.0f; c_reg = 0;
      }
    }
    int nloc = e - base; if (nloc > 64) nloc = 64;
    for (int bk = 0; bk < nloc; bk += 4) {
      int k = bk + qw;
      int ksrc = (k < 64) ? k : 0;
      float cfk = __shfl(cf_reg, ksrc);
      int ck = __shfl(c_reg, ksrc);
      if (k < nloc) {
        const uint4 hv = *reinterpret_cast<const uint4*>(hb + (size_t)ck * 64 + ql * 4);
        acc[0] += cfk * bf2f(hv.x & 0xFFFFu); acc[1] += cfk * bf2f(hv.x >> 16);
        acc[2] += cfk * bf2f(hv.y & 0xFFFFu); acc[3] += cfk * bf2f(hv.y >> 16);
        acc[4] += cfk * bf2f(hv.z & 0xFFFFu); acc[5] += cfk * bf2f(hv.z >> 16);
        acc[6] += cfk * bf2f(hv.w & 0xFFFFu); acc[7] += cfk * bf2f(hv.w >> 16);
      }
    }
  }

  #pragma unroll
  for (int i = 0; i < 8; ++i) {
    acc[i] += __shfl_xor(acc[i], 16);
    acc[i] += __shfl_xor(acc[i], 32);
  }

  if (qw == 0) {
    const int d0 = ql * 8;
    float4 b0 = *reinterpret_cast<const float4*>(bias + d0);
    float4 b1 = *reinterpret_cast<const float4*>(bias + d0 + 4);
    float4 o0, o1;
    o0.x = fmaxf(acc[0] + b0.x, 0.0f); o0.y = fmaxf(acc[1] + b0.y, 0.0f);
    o0.z = fmaxf(acc[2] + b0.z, 0.0f); o0.w = fmaxf(acc[3] + b0.w, 0.0f);
    o1.x = fmaxf(acc[4] + b1.x, 0.0f); o1.y = fmaxf(acc[5] + b1.y, 0.0f);
    o1.z = fmaxf(acc[6] + b1.z, 0.0f); o1.w = fmaxf(acc[7] + b1.w, 0.0f);
    *reinterpret_cast<float4*>(out + (size_t)wid * 128 + d0) = o0;
    *reinterpret_cast<float4*>(out + (size_t)wid * 128 + d0 + 4) = o1;
  }
}

extern "C" void kernel_launch(void* const* d_in, const int* in_sizes, int n_in,
                              void* d_out, int out_size, void* d_ws, size_t ws_size,
                              hipStream_t stream) {
  const float* seq    = (const float*)d_in[0];
  const int*   erow   = (const int*)d_in[1];
  const int*   ecol   = (const int*)d_in[2];
  const float* weight = (const float*)d_in[3];
  const float* W      = (const float*)d_in[4];
  const float* a1w    = (const float*)d_in[5];
  const float* a1b    = (const float*)d_in[6];
  const float* a2w    = (const float*)d_in[7];
  const float* a2b    = (const float*)d_in[8];
  const float* bias   = (const float*)d_in[9];
  const int N = in_sizes[0] / 256;
  const int E = in_sizes[1];
  float* out = (float*)d_out;

  char* p = (char*)d_ws;
  auto alloc = [&](size_t bytes) -> char* {
    char* q = p;
    p += (bytes + 255) & ~(size_t)255;
    return q;
  };
  unsigned* hb       = (unsigned*)alloc((size_t)N * 64 * 4);
  float*    f1       = (float*)alloc((size_t)N * 4);
  float*    f2       = (float*)alloc((size_t)N * 4);
  unsigned* rowstart = (unsigned*)alloc((size_t)(N + 1) * 4);
  const int NBKT = (N + BKT - 1) / BKT;
  unsigned* bcnt     = (unsigned*)alloc((size_t)512 * 4);
  unsigned* bstart   = (unsigned*)alloc((size_t)(NBKT + 1) * 4);
  unsigned* tail     = (unsigned*)alloc((size_t)NBKT * 4);
  uint2*    stg      = (uint2*)alloc((size_t)E * 8);
  uint2*    eb       = (uint2*)alloc((size_t)E * 8);

  init_b<<<2, 256, 0, stream>>>(bcnt, 512);
  gemm_fused<<<(N + 63) / 64, 256, 0, stream>>>(seq, W, a1w, a1b, a2w, a2b, hb, f1, f2, N);
  bhist<<<(E / 4 + 255) / 256, 256, 0, stream>>>(erow, bcnt, E, NBKT);
  bscan<<<1, 256, 0, stream>>>(bcnt, bstart, tail, NBKT);
  binA<<<(E + PCHUNK - 1) / PCHUNK, 256, 0, stream>>>(erow, ecol, weight, f1, f2, tail, stg, E, NBKT);
  binB<<<NBKT, 256, 0, stream>>>(bstart, stg, eb, rowstart, N, NBKT);
  spmm<<<(N * 64 + 255) / 256, 256, 0, stream>>>(rowstart, eb, hb, bias, out, N);
}